// Round 4
// baseline (166.693 us; speedup 1.0000x reference)
//
#include <hip/hip_runtime.h>
#include <hip/hip_cooperative_groups.h>
#include <math.h>

namespace cg = cooperative_groups;

// Problem constants (reference: B=4, L=2048)
#define LQ 2048
#define NB 4
#define NSEG 2047
#define MI 4               // i-segments per thread
#define JC 16              // j-segments per block
#define NJC 128            // j-chunks: JC*NJC = 2048 covers NSEG
#define NITILE 2           // i tiles of 1024
#define NPART (NB * NITILE * NJC)   // 1024 partials, one per block

__device__ __forceinline__ float rsq_fast(float x) { return __builtin_amdgcn_rsqf(x); }

// Build one segment record from two quaternions:
//   p = normalized(q).yzw ; dr = p1-p0 ; r = 0.5(p0+p1) ; m = r x dr
__device__ __forceinline__ void make_seg(float4 q0, float4 q1,
                                         float dr[3], float r[3], float m[3]) {
    float n2a = fmaf(q0.x, q0.x, fmaf(q0.y, q0.y, fmaf(q0.z, q0.z, q0.w * q0.w)));
    float s0  = rsq_fast(n2a);
    float ax = q0.y * s0, ay = q0.z * s0, az = q0.w * s0;
    float n2b = fmaf(q1.x, q1.x, fmaf(q1.y, q1.y, fmaf(q1.z, q1.z, q1.w * q1.w)));
    float s1  = rsq_fast(n2b);
    float bx = q1.y * s1, by = q1.z * s1, bz = q1.w * s1;
    dr[0] = bx - ax; dr[1] = by - ay; dr[2] = bz - az;
    r[0] = 0.5f * (ax + bx); r[1] = 0.5f * (ay + by); r[2] = 0.5f * (az + bz);
    m[0] = r[1] * dr[2] - r[2] * dr[1];
    m[1] = r[2] * dr[0] - r[0] * dr[2];
    m[2] = r[0] * dr[1] - r[1] * dr[0];
}

// ---------------------------------------------------------------------------
// Single cooperative kernel: all-pairs Gauss sum + grid-sync + finalize.
// num = (r_a - r_b).(dr_a x dr_b) = m_a.dr_b + dr_a.m_b  with m = r x dr.
// Grid (jc=128, itile=2, b=4) = 1024 blocks = 4 blocks/CU (co-resident via
// __launch_bounds__(256,4), LDS ~800B). Each block writes one partial slot;
// after grid.sync(), block (0,0,0) reduces all 1024 partials into d_out.
// ---------------------------------------------------------------------------
__global__ __launch_bounds__(256, 4) void gauss_coop(const float4* __restrict__ qa,
                                                     const float4* __restrict__ qb,
                                                     float* __restrict__ partials,
                                                     float* __restrict__ out) {
    const int jc    = blockIdx.x;   // 0..127
    const int itile = blockIdx.y;   // 0..1
    const int b     = blockIdx.z;   // 0..3
    const int t     = threadIdx.x;

    // --- j-records AoS in LDS: {dr(3), r(3), m(3), pad(3)}, 48B rows ---
    __shared__ __align__(16) float js[JC][12];
    if (t < JC) {
        int j = jc * JC + t;
        float dr[3] = {0.f,0.f,0.f}, r[3] = {0.f,0.f,0.f}, m[3] = {0.f,0.f,0.f};
        if (j < NSEG) {
            make_seg(qb[b * LQ + j], qb[b * LQ + j + 1], dr, r, m);
        }
        js[t][0] = dr[0]; js[t][1] = dr[1]; js[t][2] = dr[2];
        js[t][3] = r[0];  js[t][4] = r[1];  js[t][5] = r[2];
        js[t][6] = m[0];  js[t][7] = m[1];  js[t][8] = m[2];
        js[t][9] = 0.f;   js[t][10] = 0.f;  js[t][11] = 0.f;
    }

    // --- i-records per thread (coalesced quat loads, L2-resident) ---
    float dra[MI][3], ra[MI][3], ma[MI][3];
#pragma unroll
    for (int k = 0; k < MI; k++) {
        int i = itile * 1024 + k * 256 + t;
        if (i < NSEG) {
            make_seg(qa[b * LQ + i], qa[b * LQ + i + 1], dra[k], ra[k], ma[k]);
        } else {
            // zero record: num == 0 exactly, d2 = eps -> contributes 0
#pragma unroll
            for (int c = 0; c < 3; c++) { dra[k][c] = 0.f; ra[k][c] = 0.f; ma[k][c] = 0.f; }
        }
    }

    __syncthreads();

    float acc = 0.0f;
#pragma unroll
    for (int jj = 0; jj < JC; jj++) {
        const float4* r4 = (const float4*)&js[jj][0];   // broadcast ds_read_b128 x3
        float4 A = r4[0], B = r4[1], C = r4[2];
        float drbx = A.x, drby = A.y, drbz = A.z;
        float rbx  = A.w, rby  = B.x, rbz  = B.y;
        float mbx  = B.z, mby  = B.w, mbz  = C.x;
#pragma unroll
        for (int k = 0; k < MI; k++) {
            float dx = ra[k][0] - rbx;
            float dy = ra[k][1] - rby;
            float dz = ra[k][2] - rbz;
            float d2 = fmaf(dx, dx, fmaf(dy, dy, fmaf(dz, dz, 1e-12f)));
            float rs = rsq_fast(d2);
            float inv3 = (rs * rs) * rs;     // 1/dist^3
            float num = fmaf(ma[k][0], drbx,
                        fmaf(ma[k][1], drby,
                        fmaf(ma[k][2], drbz,
                        fmaf(dra[k][0], mbx,
                        fmaf(dra[k][1], mby, dra[k][2] * mbz)))));
            acc = fmaf(num, inv3, acc);
        }
    }

    // --- block reduction: wave64 shuffle, then LDS across 4 waves ---
#pragma unroll
    for (int off = 32; off > 0; off >>= 1) acc += __shfl_down(acc, off, 64);
    __shared__ float wsum[4];
    __shared__ float sb[4];
    int lane = t & 63, w = t >> 6;
    if (lane == 0) wsum[w] = acc;
    __syncthreads();
    if (t == 0) {
        // batch b's partials occupy [b*256, b*256+256)
        partials[(b * NITILE + itile) * NJC + jc] =
            wsum[0] + wsum[1] + wsum[2] + wsum[3];
    }
    __threadfence();

    cg::this_grid().sync();

    // --- finalize in block (0,0,0): out = mean_b |S_b| / (4*pi) ---
    if (blockIdx.x == 0 && blockIdx.y == 0 && blockIdx.z == 0) {
        // wave w reduces batch w's 256 partials
        const float* pb = partials + w * (NITILE * NJC);
        float s = pb[lane] + pb[64 + lane] + pb[128 + lane] + pb[192 + lane];
#pragma unroll
        for (int off = 32; off > 0; off >>= 1) s += __shfl_down(s, off, 64);
        if (lane == 0) sb[w] = fabsf(s);
        __syncthreads();
        if (t == 0) {
            out[0] = (sb[0] + sb[1] + sb[2] + sb[3]) *
                     (1.0f / NB) * (1.0f / (4.0f * 3.14159265358979323846f));
        }
    }
}

extern "C" void kernel_launch(void* const* d_in, const int* in_sizes, int n_in,
                              void* d_out, int out_size, void* d_ws, size_t ws_size,
                              hipStream_t stream) {
    const float4* qa = (const float4*)d_in[0];  // genomic_quats [B,L,4] f32
    const float4* qb = (const float4*)d_in[1];  // code_quats    [B,L,4] f32
    float* partials = (float*)d_ws;             // 1024 floats; fully overwritten
    float* out = (float*)d_out;

    void* args[] = {(void*)&qa, (void*)&qb, (void*)&partials, (void*)&out};
    hipLaunchCooperativeKernel((void*)gauss_coop,
                               dim3(NJC, NITILE, NB), dim3(256),
                               args, 0, stream);
}

// Round 5
// 90.098 us; speedup vs baseline: 1.8501x; 1.8501x over previous
//
#include <hip/hip_runtime.h>
#include <math.h>

// Problem constants (reference: B=4, L=2048)
#define LQ 2048
#define NB 4
#define NSEG 2047
#define MI 4               // i-segments per thread
#define JC 16              // j-segments per block
#define NJC 128            // j-chunks: JC*NJC = 2048 covers NSEG
#define NITILE 2           // i tiles of 1024
#define NBLK (NJC * NITILE * NB)    // 1024 blocks

// Zero-initialized module globals (untouched by harness ws/out poisoning).
// The last finishing block consumes and RESETS them, so every call (and
// every graph replay) starts from zero — no call-count dependence.
__device__ float g_acc[NB];
__device__ int   g_cnt;

__device__ __forceinline__ float rsq_fast(float x) { return __builtin_amdgcn_rsqf(x); }

// Build one segment record from two quaternions:
//   p = normalized(q).yzw ; dr = p1-p0 ; r = 0.5(p0+p1) ; m = r x dr
__device__ __forceinline__ void make_seg(float4 q0, float4 q1,
                                         float dr[3], float r[3], float m[3]) {
    float n2a = fmaf(q0.x, q0.x, fmaf(q0.y, q0.y, fmaf(q0.z, q0.z, q0.w * q0.w)));
    float s0  = rsq_fast(n2a);
    float ax = q0.y * s0, ay = q0.z * s0, az = q0.w * s0;
    float n2b = fmaf(q1.x, q1.x, fmaf(q1.y, q1.y, fmaf(q1.z, q1.z, q1.w * q1.w)));
    float s1  = rsq_fast(n2b);
    float bx = q1.y * s1, by = q1.z * s1, bz = q1.w * s1;
    dr[0] = bx - ax; dr[1] = by - ay; dr[2] = bz - az;
    r[0] = 0.5f * (ax + bx); r[1] = 0.5f * (ay + by); r[2] = 0.5f * (az + bz);
    m[0] = r[1] * dr[2] - r[2] * dr[1];
    m[1] = r[2] * dr[0] - r[0] * dr[2];
    m[2] = r[0] * dr[1] - r[1] * dr[0];
}

// ---------------------------------------------------------------------------
// Single ordinary kernel: all-pairs Gauss sum, last-block finalize.
// num = (r_a - r_b).(dr_a x dr_b) = m_a.dr_b + dr_a.m_b  with m = r x dr.
// Grid (jc=128, itile=2, b=4) = 1024 blocks, 256 threads. Thread owns MI=4
// i's; block owns JC=16 j's staged AoS in LDS (broadcast ds_read_b128).
// Block partial -> device-scope atomicAdd into g_acc[b]; ticket counter;
// the 1024th block computes out = mean_b |S_b| / (4*pi) and resets globals.
// ---------------------------------------------------------------------------
__global__ __launch_bounds__(256) void pair_fused(const float4* __restrict__ qa,
                                                  const float4* __restrict__ qb,
                                                  float* __restrict__ out) {
    const int jc    = blockIdx.x;   // 0..127
    const int itile = blockIdx.y;   // 0..1
    const int b     = blockIdx.z;   // 0..3
    const int t     = threadIdx.x;

    // --- j-records AoS in LDS: {dr(3), r(3), m(3), pad(3)}, 48B rows ---
    __shared__ __align__(16) float js[JC][12];
    if (t < JC) {
        int j = jc * JC + t;
        float dr[3] = {0.f,0.f,0.f}, r[3] = {0.f,0.f,0.f}, m[3] = {0.f,0.f,0.f};
        if (j < NSEG) {
            make_seg(qb[b * LQ + j], qb[b * LQ + j + 1], dr, r, m);
        }
        js[t][0] = dr[0]; js[t][1] = dr[1]; js[t][2] = dr[2];
        js[t][3] = r[0];  js[t][4] = r[1];  js[t][5] = r[2];
        js[t][6] = m[0];  js[t][7] = m[1];  js[t][8] = m[2];
        js[t][9] = 0.f;   js[t][10] = 0.f;  js[t][11] = 0.f;
    }

    // --- i-records per thread (coalesced quat loads, L2/L3-resident) ---
    float dra[MI][3], ra[MI][3], ma[MI][3];
#pragma unroll
    for (int k = 0; k < MI; k++) {
        int i = itile * 1024 + k * 256 + t;
        if (i < NSEG) {
            make_seg(qa[b * LQ + i], qa[b * LQ + i + 1], dra[k], ra[k], ma[k]);
        } else {
            // zero record: num == 0 exactly, d2 = eps -> contributes 0
#pragma unroll
            for (int c = 0; c < 3; c++) { dra[k][c] = 0.f; ra[k][c] = 0.f; ma[k][c] = 0.f; }
        }
    }

    __syncthreads();

    float acc = 0.0f;
#pragma unroll
    for (int jj = 0; jj < JC; jj++) {
        const float4* r4 = (const float4*)&js[jj][0];   // 3x broadcast ds_read_b128
        float4 A = r4[0], B = r4[1], C = r4[2];
        float drbx = A.x, drby = A.y, drbz = A.z;
        float rbx  = A.w, rby  = B.x, rbz  = B.y;
        float mbx  = B.z, mby  = B.w, mbz  = C.x;
#pragma unroll
        for (int k = 0; k < MI; k++) {
            float dx = ra[k][0] - rbx;
            float dy = ra[k][1] - rby;
            float dz = ra[k][2] - rbz;
            float d2 = fmaf(dx, dx, fmaf(dy, dy, fmaf(dz, dz, 1e-12f)));
            float rs = rsq_fast(d2);
            float inv3 = (rs * rs) * rs;     // 1/dist^3
            float num = fmaf(ma[k][0], drbx,
                        fmaf(ma[k][1], drby,
                        fmaf(ma[k][2], drbz,
                        fmaf(dra[k][0], mbx,
                        fmaf(dra[k][1], mby, dra[k][2] * mbz)))));
            acc = fmaf(num, inv3, acc);
        }
    }

    // --- block reduction: wave64 shuffle, then LDS across 4 waves ---
#pragma unroll
    for (int off = 32; off > 0; off >>= 1) acc += __shfl_down(acc, off, 64);
    __shared__ float wsum[4];
    int lane = t & 63, w = t >> 6;
    if (lane == 0) wsum[w] = acc;
    __syncthreads();

    if (t == 0) {
        float tot = wsum[0] + wsum[1] + wsum[2] + wsum[3];
        atomicAdd(&g_acc[b], tot);                       // device scope by default
        __threadfence();                                 // release our add
        int old = __hip_atomic_fetch_add(&g_cnt, 1, __ATOMIC_ACQ_REL,
                                         __HIP_MEMORY_SCOPE_AGENT);
        if (old == NBLK - 1) {
            __threadfence();                             // acquire all adds
            float s = 0.0f;
#pragma unroll
            for (int q = 0; q < NB; q++) {
                float v = __hip_atomic_load(&g_acc[q], __ATOMIC_RELAXED,
                                            __HIP_MEMORY_SCOPE_AGENT);
                s += fabsf(v);
                __hip_atomic_store(&g_acc[q], 0.0f, __ATOMIC_RELAXED,
                                   __HIP_MEMORY_SCOPE_AGENT);   // reset for next call
            }
            out[0] = s * (1.0f / NB) * (1.0f / (4.0f * 3.14159265358979323846f));
            __hip_atomic_store(&g_cnt, 0, __ATOMIC_RELEASE,
                               __HIP_MEMORY_SCOPE_AGENT);       // reset ticket
        }
    }
}

extern "C" void kernel_launch(void* const* d_in, const int* in_sizes, int n_in,
                              void* d_out, int out_size, void* d_ws, size_t ws_size,
                              hipStream_t stream) {
    const float4* qa = (const float4*)d_in[0];  // genomic_quats [B,L,4] f32
    const float4* qb = (const float4*)d_in[1];  // code_quats    [B,L,4] f32
    float* out = (float*)d_out;
    (void)d_ws; (void)ws_size;

    pair_fused<<<dim3(NJC, NITILE, NB), dim3(256), 0, stream>>>(qa, qb, out);
}

// Round 6
// 64.568 us; speedup vs baseline: 2.5817x; 1.3954x over previous
//
#include <hip/hip_runtime.h>
#include <math.h>

// Problem constants (reference: B=4, L=2048)
#define LQ 2048
#define NB 4
#define NSEG 2047
#define MI 2                 // i-segments per thread (named regs, no arrays)
#define JC 16                // j-segments per block
#define NJC 128              // j-chunks: JC*NJC = 2048 covers NSEG
#define NITILE 4             // i tiles of MI*256 = 512
#define PARTIALS_PER_B (NITILE * NJC)   // 512 partials per batch
#define NPART (NB * PARTIALS_PER_B)     // 2048 partials total

__device__ __forceinline__ float rsq_fast(float x) { return __builtin_amdgcn_rsqf(x); }

// Segment record as a by-value named-field struct: SROA keeps it in VGPRs
// (float[MI][3] arrays + pointer out-params were demoted to scratch: r4/r5
// showed VGPR_Count=28, i.e. spilled records -> latency-bound inner loop).
struct Seg {
    float drx, dry, drz;   // tangent dr = p1 - p0
    float rx,  ry,  rz;    // midpoint r = 0.5(p0+p1)
    float mx,  my,  mz;    // moment m = r x dr
};

__device__ __forceinline__ Seg zero_seg() {
    Seg s;
    s.drx = s.dry = s.drz = 0.f;
    s.rx  = s.ry  = s.rz  = 0.f;
    s.mx  = s.my  = s.mz  = 0.f;
    return s;
}

__device__ __forceinline__ Seg make_seg(float4 q0, float4 q1) {
    float n2a = fmaf(q0.x, q0.x, fmaf(q0.y, q0.y, fmaf(q0.z, q0.z, q0.w * q0.w)));
    float s0  = rsq_fast(n2a);
    float ax = q0.y * s0, ay = q0.z * s0, az = q0.w * s0;
    float n2b = fmaf(q1.x, q1.x, fmaf(q1.y, q1.y, fmaf(q1.z, q1.z, q1.w * q1.w)));
    float s1  = rsq_fast(n2b);
    float bx = q1.y * s1, by = q1.z * s1, bz = q1.w * s1;
    Seg s;
    s.drx = bx - ax; s.dry = by - ay; s.drz = bz - az;
    s.rx = 0.5f * (ax + bx); s.ry = 0.5f * (ay + by); s.rz = 0.5f * (az + bz);
    s.mx = s.ry * s.drz - s.rz * s.dry;
    s.my = s.rz * s.drx - s.rx * s.drz;
    s.mz = s.rx * s.dry - s.ry * s.drx;
    return s;
}

// ---------------------------------------------------------------------------
// All-pairs Gauss sum. num = (r_a-r_b).(dr_a x dr_b) = m_a.dr_b + dr_a.m_b.
// Grid (jc=128, itile=4, b=4) = 2048 blocks x 256 thr = 8 blocks/CU (full
// 2048-thread slot capacity -> ~8 waves/SIMD latency hiding). Thread owns
// MI=2 i's in named structs; block stages JC=16 j-records AoS in LDS
// (broadcast ds_read_b128 x3 per j). One partial per block into d_ws.
// No atomics, no device fences (r5: those cost +26 us in single-wave tails).
// ---------------------------------------------------------------------------
__global__ __launch_bounds__(256) void pair_fused(const float4* __restrict__ qa,
                                                  const float4* __restrict__ qb,
                                                  float* __restrict__ partials) {
    const int jc    = blockIdx.x;   // 0..127
    const int itile = blockIdx.y;   // 0..3
    const int b     = blockIdx.z;   // 0..3
    const int t     = threadIdx.x;

    // --- j-records AoS in LDS: {dr(3), r(3), m(3), pad(3)}, 48B rows ---
    __shared__ __align__(16) float js[JC][12];
    if (t < JC) {
        int j = jc * JC + t;
        Seg s = (j < NSEG) ? make_seg(qb[b * LQ + j], qb[b * LQ + j + 1]) : zero_seg();
        js[t][0] = s.drx; js[t][1] = s.dry; js[t][2]  = s.drz;
        js[t][3] = s.rx;  js[t][4] = s.ry;  js[t][5]  = s.rz;
        js[t][6] = s.mx;  js[t][7] = s.my;  js[t][8]  = s.mz;
        js[t][9] = 0.f;   js[t][10] = 0.f;  js[t][11] = 0.f;
    }

    // --- i-records in named registers (coalesced quat loads, L2-resident) ---
    const int i0 = itile * (MI * 256) + t;
    const int i1 = i0 + 256;
    Seg a0 = (i0 < NSEG) ? make_seg(qa[b * LQ + i0], qa[b * LQ + i0 + 1]) : zero_seg();
    Seg a1 = (i1 < NSEG) ? make_seg(qa[b * LQ + i1], qa[b * LQ + i1 + 1]) : zero_seg();

    __syncthreads();

    float acc0 = 0.0f, acc1 = 0.0f;
#pragma unroll 4
    for (int jj = 0; jj < JC; jj++) {
        const float4* r4 = (const float4*)&js[jj][0];   // 3x broadcast ds_read_b128
        float4 A = r4[0], B = r4[1], C = r4[2];
        float drbx = A.x, drby = A.y, drbz = A.z;
        float rbx  = A.w, rby  = B.x, rbz  = B.y;
        float mbx  = B.z, mby  = B.w, mbz  = C.x;

        {   // i0
            float dx = a0.rx - rbx, dy = a0.ry - rby, dz = a0.rz - rbz;
            float d2 = fmaf(dx, dx, fmaf(dy, dy, fmaf(dz, dz, 1e-12f)));
            float rs = rsq_fast(d2);
            float inv3 = (rs * rs) * rs;
            float num = fmaf(a0.mx, drbx,
                        fmaf(a0.my, drby,
                        fmaf(a0.mz, drbz,
                        fmaf(a0.drx, mbx,
                        fmaf(a0.dry, mby, a0.drz * mbz)))));
            acc0 = fmaf(num, inv3, acc0);
        }
        {   // i1
            float dx = a1.rx - rbx, dy = a1.ry - rby, dz = a1.rz - rbz;
            float d2 = fmaf(dx, dx, fmaf(dy, dy, fmaf(dz, dz, 1e-12f)));
            float rs = rsq_fast(d2);
            float inv3 = (rs * rs) * rs;
            float num = fmaf(a1.mx, drbx,
                        fmaf(a1.my, drby,
                        fmaf(a1.mz, drbz,
                        fmaf(a1.drx, mbx,
                        fmaf(a1.dry, mby, a1.drz * mbz)))));
            acc1 = fmaf(num, inv3, acc1);
        }
    }
    float acc = acc0 + acc1;

    // --- block reduction: wave64 shuffle, then LDS across 4 waves ---
#pragma unroll
    for (int off = 32; off > 0; off >>= 1) acc += __shfl_down(acc, off, 64);
    __shared__ float wsum[4];
    int lane = t & 63, w = t >> 6;
    if (lane == 0) wsum[w] = acc;
    __syncthreads();
    if (t == 0) {
        partials[(b * NITILE + itile) * NJC + jc] =
            wsum[0] + wsum[1] + wsum[2] + wsum[3];
    }
}

// ---------------------------------------------------------------------------
// Finalize: wave w reduces batch w's 512 partials; out = mean_b |S_b|/(4*pi)
// ---------------------------------------------------------------------------
__global__ __launch_bounds__(256) void finalize_kernel(const float* __restrict__ partials,
                                                       float* __restrict__ out) {
    int t = threadIdx.x;
    int w = t >> 6, lane = t & 63;
    const float* pb = partials + w * PARTIALS_PER_B;
    float s = 0.0f;
#pragma unroll
    for (int r = 0; r < PARTIALS_PER_B / 64; r++)
        s += pb[r * 64 + lane];
#pragma unroll
    for (int off = 32; off > 0; off >>= 1) s += __shfl_down(s, off, 64);
    __shared__ float sb[4];
    if (lane == 0) sb[w] = fabsf(s);
    __syncthreads();
    if (t == 0) {
        out[0] = (sb[0] + sb[1] + sb[2] + sb[3]) *
                 (1.0f / NB) * (1.0f / (4.0f * 3.14159265358979323846f));
    }
}

extern "C" void kernel_launch(void* const* d_in, const int* in_sizes, int n_in,
                              void* d_out, int out_size, void* d_ws, size_t ws_size,
                              hipStream_t stream) {
    const float4* qa = (const float4*)d_in[0];  // genomic_quats [B,L,4] f32
    const float4* qb = (const float4*)d_in[1];  // code_quats    [B,L,4] f32
    float* partials = (float*)d_ws;             // 2048 floats; fully overwritten
    float* out = (float*)d_out;

    pair_fused<<<dim3(NJC, NITILE, NB), dim3(256), 0, stream>>>(qa, qb, partials);
    finalize_kernel<<<dim3(1), dim3(256), 0, stream>>>(partials, out);
}